// Round 1
// baseline (1495.816 us; speedup 1.0000x reference)
//
#include <hip/hip_runtime.h>

typedef __attribute__((ext_vector_type(8))) short bf16x8;
typedef __attribute__((ext_vector_type(4))) float f32x4;

__device__ __forceinline__ unsigned short f2bf(float f) {
  unsigned u = __builtin_bit_cast(unsigned, f);
  u += 0x7fffu + ((u >> 16) & 1u);   // round-to-nearest-even
  return (unsigned short)(u >> 16);
}
__device__ __forceinline__ float bf2f(unsigned short s) {
  unsigned u = ((unsigned)s) << 16;
  return __builtin_bit_cast(float, u);
}
__device__ __forceinline__ bf16x8 zero8() {
  bf16x8 r;
#pragma unroll
  for (int i = 0; i < 8; ++i) r[i] = 0;
  return r;
}

// One wave processes a batch of 16 nodes: per-node GAT+maxpool (MFMA1+MFMA2),
// then a 16-node-batched GRU via MFMA. LDS: bf16-transposed GRU weights
// (shared) + small per-wave scratch. 74KB/block -> 2 blocks/CU.
__global__ __launch_bounds__(256, 2) void rann_fused(
    const float* __restrict__ nf, const float* __restrict__ ch,
    const float* __restrict__ Ac, const int* __restrict__ ccnt,
    const float* __restrict__ W, const float* __restrict__ a_src,
    const float* __restrict__ a_dst, const float* __restrict__ Wx,
    const float* __restrict__ Whg, const float* __restrict__ bias,
    float* __restrict__ out, int N) {
  __shared__ __align__(16) unsigned short whgT[192][72];  // [col][h], 144B rows
  __shared__ __align__(16) unsigned short wxT[192][72];   // [col][k<40 real]
  __shared__ __align__(16) float b_lds[192];
  __shared__ __align__(16) float srcdst[4][32];           // per-wave: src[16],dst[16]
  __shared__ __align__(16) unsigned short wh_t[4][64][16];   // per-wave: Wh^T bf16 [k'][j]
  __shared__ __align__(16) unsigned short pooledb[4][16][72]; // per-wave: pooled bf16 [node][h]

  const int tid = threadIdx.x;
  // ---- stage GRU weights transposed to bf16 (B-operand friendly) ----
  for (int idx = tid; idx < 192 * 64; idx += 256) {
    const int col = idx % 192, k = idx / 192;
    whgT[col][k] = f2bf(Whg[k * 192 + col]);
    wxT[col][k] = (k < 40) ? f2bf(Wx[k * 192 + col]) : (unsigned short)0;
  }
  if (tid < 192) b_lds[tid] = bias[tid];
  __syncthreads();

  const int lane = tid & 63;
  const int w = tid >> 6;
  const int q = lane >> 4;     // quad
  const int m16 = lane & 15;

  // ---- persistent W B-frags: B[k=8q+j][n=16u+m16], k-tile t ----
  bf16x8 wfrag[2][4];
#pragma unroll
  for (int t = 0; t < 2; ++t)
#pragma unroll
    for (int u = 0; u < 4; ++u) {
      bf16x8 f;
#pragma unroll
      for (int j = 0; j < 8; ++j)
        f[j] = (short)f2bf(W[(32 * t + 8 * q + j) * 64 + 16 * u + m16]);
      wfrag[t][u] = f;
    }
  float asv[4], adv[4];
#pragma unroll
  for (int u = 0; u < 4; ++u) {
    asv[u] = a_src[16 * u + m16];
    adv[u] = a_dst[16 * u + m16];
  }

  const int gwave = blockIdx.x * 4 + w;
  const int stride = gridDim.x * 4;
  const int nbatch = N >> 4;  // N divisible by 16 (200000)
  for (int bidx = gwave; bidx < nbatch; bidx += stride) {
    const int nb = bidx << 4;
    // ================= attention + pool, one node at a time =================
    for (int s = 0; s < 16; ++s) {
      const int n = nb + s;
      const int cc = ccnt[n];
      // A-frag of child_hiddens: A[m=c][k=h], lane loads 8 contiguous h
      bf16x8 afA[2];
#pragma unroll
      for (int t = 0; t < 2; ++t) {
        const float* p = ch + (size_t)n * 1024 + m16 * 64 + 32 * t + 8 * q;
        f32x4 v0 = *(const f32x4*)p;
        f32x4 v1 = *(const f32x4*)(p + 4);
        bf16x8 f;
#pragma unroll
        for (int j = 0; j < 4; ++j) {
          f[j] = (short)f2bf(v0[j]);
          f[j + 4] = (short)f2bf(v1[j]);
        }
        afA[t] = f;
      }
      // Wh = ch @ W : C-layout D[row=4q+r][col=16u+m16]
      f32x4 acc[4];
#pragma unroll
      for (int u = 0; u < 4; ++u) acc[u] = (f32x4){0.f, 0.f, 0.f, 0.f};
#pragma unroll
      for (int t = 0; t < 2; ++t)
#pragma unroll
        for (int u = 0; u < 4; ++u)
          acc[u] = __builtin_amdgcn_mfma_f32_16x16x32_bf16(afA[t], wfrag[t][u], acc[u], 0, 0, 0);

      // src[c]=Wh[c]·a_src, dst[c]=Wh[c]·a_dst via butterfly over m16
      float ps[4], pd[4];
#pragma unroll
      for (int r = 0; r < 4; ++r) {
        ps[r] = acc[0][r] * asv[0] + acc[1][r] * asv[1] + acc[2][r] * asv[2] + acc[3][r] * asv[3];
        pd[r] = acc[0][r] * adv[0] + acc[1][r] * adv[1] + acc[2][r] * adv[2] + acc[3][r] * adv[3];
      }
#pragma unroll
      for (int m = 1; m < 16; m <<= 1) {
#pragma unroll
        for (int r = 0; r < 4; ++r) {
          ps[r] += __shfl_xor(ps[r], m);
          pd[r] += __shfl_xor(pd[r], m);
        }
      }
      if (m16 == 0) {
        *(f32x4*)&srcdst[w][4 * q] = (f32x4){ps[0], ps[1], ps[2], ps[3]};
        *(f32x4*)&srcdst[w][16 + 4 * q] = (f32x4){pd[0], pd[1], pd[2], pd[3]};
      }
      // Wh -> bf16 LDS transpose wh_t[k'][j] for MFMA2 B-operand
#pragma unroll
      for (int u = 0; u < 4; ++u) {
        uint2 v;
        v.x = (unsigned)f2bf(acc[u][0]) | ((unsigned)f2bf(acc[u][1]) << 16);
        v.y = (unsigned)f2bf(acc[u][2]) | ((unsigned)f2bf(acc[u][3]) << 16);
        *(uint2*)&wh_t[w][16 * u + m16][4 * q] = v;
      }
      __threadfence_block();  // order per-wave LDS writes before reads

      // e + masked softmax, computed directly in A-operand layout:
      // row i = m16, cols j = 8*qe + jj (q>=2 mirrors q-2; its frag is zeroed)
      const int qe = q & 1;
      const float srcv = srcdst[w][m16];
      f32x4 d0 = *(const f32x4*)&srcdst[w][16 + 8 * qe];
      f32x4 d1 = *(const f32x4*)&srcdst[w][16 + 8 * qe + 4];
      const float* ap = Ac + (size_t)n * 256 + m16 * 16 + 8 * qe;
      f32x4 a0 = *(const f32x4*)ap;
      f32x4 a1 = *(const f32x4*)(ap + 4);
      float p8[8];
      float rmax = -3.0e38f;
#pragma unroll
      for (int jj = 0; jj < 8; ++jj) {
        const float dstv = (jj < 4) ? d0[jj] : d1[jj - 4];
        const float av = (jj < 4) ? a0[jj] : a1[jj - 4];
        const float x = srcv + dstv;
        const float e = fmaxf(x, 0.2f * x);  // leaky_relu(x,0.2)
        const bool msk = (av > 0.5f) && (m16 < cc) && ((8 * qe + jj) < cc);
        p8[jj] = msk ? e : -1.0e9f;
        rmax = fmaxf(rmax, p8[jj]);
      }
      rmax = fmaxf(rmax, __shfl_xor(rmax, 16));
      float psum = 0.f;
#pragma unroll
      for (int jj = 0; jj < 8; ++jj) {
        p8[jj] = __expf(p8[jj] - rmax);
        psum += p8[jj];
      }
      psum += __shfl_xor(psum, 16);
      const float inv = 1.0f / psum;
      bf16x8 afrag2 = zero8();
      if (q < 2) {
#pragma unroll
        for (int jj = 0; jj < 8; ++jj) afrag2[jj] = (short)f2bf(p8[jj] * inv);
      }
      // h_msg = attn @ Wh (K=16 padded to 32 with zero frags)
      f32x4 acc2[4];
#pragma unroll
      for (int u = 0; u < 4; ++u) {
        bf16x8 bf2 = zero8();
        if (q < 2) bf2 = *(const bf16x8*)&wh_t[w][16 * u + m16][8 * q];
        f32x4 z4 = (f32x4){0.f, 0.f, 0.f, 0.f};
        acc2[u] = __builtin_amdgcn_mfma_f32_16x16x32_bf16(afrag2, bf2, z4, 0, 0, 0);
      }
      // elu + masked max-pool over children; result broadcast to all lanes
#pragma unroll
      for (int u = 0; u < 4; ++u) {
        float pm = -1.0e9f;
#pragma unroll
        for (int r = 0; r < 4; ++r) {
          const float v = acc2[u][r];
          const float ev = v > 0.f ? v : __expf(v) - 1.0f;
          pm = fmaxf(pm, (4 * q + r) < cc ? ev : -1.0e9f);
        }
        pm = fmaxf(pm, __shfl_xor(pm, 16));
        pm = fmaxf(pm, __shfl_xor(pm, 32));
        if (q == 0) pooledb[w][s][16 * u + m16] = f2bf(pm);
      }
    }  // s loop
    __threadfence_block();

    // ================= GRU, 16 nodes batched as MFMA M-dim =================
    bf16x8 afP[2];  // A[m=node][k=h] from pooled
#pragma unroll
    for (int t = 0; t < 2; ++t)
      afP[t] = *(const bf16x8*)&pooledb[w][m16][32 * t + 8 * q];
    bf16x8 afX[2];  // A[m=node][k<40] from node_features
    {
      const float* p = nf + (size_t)(nb + m16) * 40 + 8 * q;
      f32x4 v0 = *(const f32x4*)p;
      f32x4 v1 = *(const f32x4*)(p + 4);
      bf16x8 f;
#pragma unroll
      for (int j = 0; j < 4; ++j) {
        f[j] = (short)f2bf(v0[j]);
        f[j + 4] = (short)f2bf(v1[j]);
      }
      afX[0] = f;
      afX[1] = zero8();
      if (q == 0) {  // k = 32..39 real, rest zero-padded
        const float* p1 = nf + (size_t)(nb + m16) * 40 + 32;
        f32x4 w0 = *(const f32x4*)p1;
        f32x4 w1 = *(const f32x4*)(p1 + 4);
        bf16x8 g;
#pragma unroll
        for (int j = 0; j < 4; ++j) {
          g[j] = (short)f2bf(w0[j]);
          g[j + 4] = (short)f2bf(w1[j]);
        }
        afX[1] = g;
      }
    }
    // cols 0..127 (z,r gates): gx+gh share an accumulator; cols 128..191 separate
    f32x4 accS[8], accX4[4], accH4[4];
#pragma unroll
    for (int u = 0; u < 8; ++u) accS[u] = (f32x4){0.f, 0.f, 0.f, 0.f};
#pragma unroll
    for (int u = 0; u < 4; ++u) {
      accX4[u] = (f32x4){0.f, 0.f, 0.f, 0.f};
      accH4[u] = (f32x4){0.f, 0.f, 0.f, 0.f};
    }
#pragma unroll
    for (int u = 0; u < 8; ++u) {
      const int row = 16 * u + m16;
#pragma unroll
      for (int t = 0; t < 2; ++t) {
        accS[u] = __builtin_amdgcn_mfma_f32_16x16x32_bf16(
            afP[t], *(const bf16x8*)&whgT[row][32 * t + 8 * q], accS[u], 0, 0, 0);
        accS[u] = __builtin_amdgcn_mfma_f32_16x16x32_bf16(
            afX[t], *(const bf16x8*)&wxT[row][32 * t + 8 * q], accS[u], 0, 0, 0);
      }
    }
#pragma unroll
    for (int u = 0; u < 4; ++u) {
      const int row = 128 + 16 * u + m16;
#pragma unroll
      for (int t = 0; t < 2; ++t) {
        accH4[u] = __builtin_amdgcn_mfma_f32_16x16x32_bf16(
            afP[t], *(const bf16x8*)&whgT[row][32 * t + 8 * q], accH4[u], 0, 0, 0);
        accX4[u] = __builtin_amdgcn_mfma_f32_16x16x32_bf16(
            afX[t], *(const bf16x8*)&wxT[row][32 * t + 8 * q], accX4[u], 0, 0, 0);
      }
    }
    // epilogue: lane holds node 4q+r, col 16u+m16
#pragma unroll
    for (int u = 0; u < 4; ++u) {
      const int col = 16 * u + m16;
      const float bz = b_lds[col];
      const float br = b_lds[64 + col];
      const float bn = b_lds[128 + col];
#pragma unroll
      for (int r = 0; r < 4; ++r) {
        const int nl = 4 * q + r;
        const float z = 1.0f / (1.0f + __expf(-(accS[u][r] + bz)));
        const float rg = 1.0f / (1.0f + __expf(-(accS[u + 4][r] + br)));
        const float nn = tanhf(accX4[u][r] + bn + rg * accH4[u][r]);
        const float pv = bf2f(pooledb[w][nl][col]);
        out[(size_t)(nb + nl) * 64 + col] = (1.0f - z) * nn + z * pv;
      }
    }
  }
}

extern "C" void kernel_launch(void* const* d_in, const int* in_sizes, int n_in,
                              void* d_out, int out_size, void* d_ws, size_t ws_size,
                              hipStream_t stream) {
  const float* nf = (const float*)d_in[0];
  const float* ch = (const float*)d_in[1];
  const float* Ac = (const float*)d_in[2];
  const int* ccnt = (const int*)d_in[3];
  const float* W = (const float*)d_in[4];
  const float* a_src = (const float*)d_in[5];
  const float* a_dst = (const float*)d_in[6];
  const float* Wx = (const float*)d_in[7];
  const float* Whg = (const float*)d_in[8];
  const float* bias = (const float*)d_in[9];
  float* out = (float*)d_out;
  const int N = in_sizes[3];  // child_count is [N]
  const int nbatch = N >> 4;
  int blocks = 625;  // 2500 waves, 5 batches each at N=200k
  if (blocks > (nbatch + 3) / 4) blocks = (nbatch + 3) / 4;
  if (blocks < 1) blocks = 1;
  hipLaunchKernelGGL(rann_fused, dim3(blocks), dim3(256), 0, stream,
                     nf, ch, Ac, ccnt, W, a_src, a_dst, Wx, Whg, bias, out, N);
}